// Round 10
// baseline (206.500 us; speedup 1.0000x reference)
//
#include <hip/hip_runtime.h>
#include <hip/hip_cooperative_groups.h>

namespace cg = cooperative_groups;

// Problem constants: B=4, N=256, E=512, fp32.
#define B_ 4
#define N_ 256
#define E_ 512

// ws float layout:
//   QwT  [256*256]        @ 0
//   Gpart[16][256*256]    @ OFF_GP   (slab = kq*4+b, kq: K/128 chunk)
//   Spart[16][256*256]    @ OFF_SP   (slab = kq*4+b; only kq<=it written)
//   Tpart[16][256*256]    @ OFF_TP   (slab = kp*4+b; only kp<=it written)
#define OFF_GP 65536
#define OFF_SP 1114112
#define OFF_TP 2162688

// ---------------------------------------------------------------------------
// Single cooperative kernel: gram+transpose | sync | sgemm | sync | tgemm |
// sync | final.  grid 272 x (16,16).  LDS: two 64x68 fp32 tiles (34.8 KB).
// ---------------------------------------------------------------------------
__global__ __launch_bounds__(256, 4) void mono_kernel(
    const float* __restrict__ X, const float* __restrict__ Qw,
    const float* __restrict__ Kw, float* __restrict__ ws,
    float* __restrict__ out) {

    cg::grid_group grid = cg::this_grid();

    __shared__ float lds[2 * 64 * 68];          // 34816 B
    float* const At = lds;                      // [64][68] flat
    float* const Bt = lds + 64 * 68;

    const int blk = blockIdx.x;
    const int tx = threadIdx.x, ty = threadIdx.y;
    const int tid = ty * 16 + tx;

    float* const QwT   = ws;
    float* const Gpart = ws + OFF_GP;
    float* const Spart = ws + OFF_SP;
    float* const Tpart = ws + OFF_TP;

    // ================= Phase 1: Gram split-K partials (0..255) + QwT (256..271)
    if (blk < 256) {
        const int kq = blk >> 6;
        const int rem = blk & 63;
        const int b = rem >> 4;
        const int tileid = rem & 15;
        const int by = tileid >> 2, bx = tileid & 3;
        const float* __restrict__ Xb = X + (size_t)b * N_ * E_;
        float acc[4][4] = {};
        const int r = tid >> 2, c0 = tid & 3;

        for (int k0 = kq * 128; k0 < kq * 128 + 128; k0 += 32) {
            {
                const float4 va = *(const float4*)&Xb[(size_t)(by * 64 + r) * E_ + k0 + c0 * 8];
                const float4 vb = *(const float4*)&Xb[(size_t)(by * 64 + r) * E_ + k0 + c0 * 8 + 4];
                At[(c0*8+0)*68+r] = va.x; At[(c0*8+1)*68+r] = va.y;
                At[(c0*8+2)*68+r] = va.z; At[(c0*8+3)*68+r] = va.w;
                At[(c0*8+4)*68+r] = vb.x; At[(c0*8+5)*68+r] = vb.y;
                At[(c0*8+6)*68+r] = vb.z; At[(c0*8+7)*68+r] = vb.w;
                const float4 wa = *(const float4*)&Xb[(size_t)(bx * 64 + r) * E_ + k0 + c0 * 8];
                const float4 wb = *(const float4*)&Xb[(size_t)(bx * 64 + r) * E_ + k0 + c0 * 8 + 4];
                Bt[(c0*8+0)*68+r] = wa.x; Bt[(c0*8+1)*68+r] = wa.y;
                Bt[(c0*8+2)*68+r] = wa.z; Bt[(c0*8+3)*68+r] = wa.w;
                Bt[(c0*8+4)*68+r] = wb.x; Bt[(c0*8+5)*68+r] = wb.y;
                Bt[(c0*8+6)*68+r] = wb.z; Bt[(c0*8+7)*68+r] = wb.w;
            }
            __syncthreads();
#pragma unroll
            for (int kk = 0; kk < 32; ++kk) {
                const float4 a  = *(const float4*)&At[kk * 68 + ty * 4];
                const float4 bb = *(const float4*)&Bt[kk * 68 + tx * 4];
                acc[0][0] += a.x*bb.x; acc[0][1] += a.x*bb.y; acc[0][2] += a.x*bb.z; acc[0][3] += a.x*bb.w;
                acc[1][0] += a.y*bb.x; acc[1][1] += a.y*bb.y; acc[1][2] += a.y*bb.z; acc[1][3] += a.y*bb.w;
                acc[2][0] += a.z*bb.x; acc[2][1] += a.z*bb.y; acc[2][2] += a.z*bb.z; acc[2][3] += a.z*bb.w;
                acc[3][0] += a.w*bb.x; acc[3][1] += a.w*bb.y; acc[3][2] += a.w*bb.z; acc[3][3] += a.w*bb.w;
            }
            __syncthreads();
        }
        float* gout = Gpart + ((size_t)(kq * 4 + b) * N_ + by * 64 + ty * 4) * N_ + bx * 64 + tx * 4;
#pragma unroll
        for (int ri = 0; ri < 4; ++ri)
            *(float4*)&gout[(size_t)ri * N_] =
                make_float4(acc[ri][0], acc[ri][1], acc[ri][2], acc[ri][3]);
    } else {
        // ---- Qw transpose, 16 jobs of 64x64
        const int t = blk - 256;
        const int bxt = t & 3, byt = t >> 2;
        const int r = tid >> 2, c0 = tid & 3;
#pragma unroll
        for (int cc = 0; cc < 4; ++cc) {
            const int c = (c0 + cc * 4) * 4;
            const float4 v = *(const float4*)&Qw[(byt * 64 + r) * N_ + bxt * 64 + c];
            At[(c+0)*68+r] = v.x; At[(c+1)*68+r] = v.y;
            At[(c+2)*68+r] = v.z; At[(c+3)*68+r] = v.w;
        }
        __syncthreads();
#pragma unroll
        for (int cc = 0; cc < 4; ++cc) {
            const int c = (c0 + cc * 4) * 4;
            const float4 v = *(const float4*)&At[r * 68 + c];
            *(float4*)&QwT[(bxt * 64 + r) * N_ + byt * 64 + c] = v;
        }
    }

    grid.sync();

    // ================= Phase 2: sgemm (120 jobs): Spart[kq][b] tiles
    if (blk < 120) {
        const int b = blk / 30;
        const int r2 = blk % 30;
        int it, pt, kq;
        if (r2 < 1)       { it = 0; pt = 0;              kq = 0; }
        else if (r2 < 5)  { it = 1; const int q = r2-1;  pt = q >> 1; kq = q & 1; }
        else if (r2 < 14) { it = 2; const int q = r2-5;  pt = q / 3;  kq = q % 3; }
        else              { it = 3; const int q = r2-14; pt = q >> 2; kq = q & 3; }

        // ---- stage A: G rows it*64.., cols kq*64.., sum 4 slabs, diag mask
        {
            const int i_loc = tid >> 2, c0 = tid & 3;
            float av[16];
#pragma unroll
            for (int e = 0; e < 16; ++e) av[e] = 0.f;
#pragma unroll
            for (int q = 0; q < 4; ++q) {
                const float* src = Gpart + ((size_t)(q * 4 + b) * N_ + it * 64 + i_loc) * N_
                                 + kq * 64 + c0 * 16;
#pragma unroll
                for (int v = 0; v < 4; ++v) {
                    const float4 f = *(const float4*)&src[v * 4];
                    av[v*4+0] += f.x; av[v*4+1] += f.y; av[v*4+2] += f.z; av[v*4+3] += f.w;
                }
            }
            if (kq == it) {
#pragma unroll
                for (int e = 0; e < 16; ++e)
                    if (c0 * 16 + e > i_loc) av[e] = 0.f;
            }
#pragma unroll
            for (int e = 0; e < 16; ++e) At[(c0 * 16 + e) * 68 + i_loc] = av[e];
        }
        // ---- stage B: Kw rows kq*64.., cols pt*64..
        {
            const int k = tid >> 2, c0 = tid & 3;
            const float* src = Kw + (size_t)(kq * 64 + k) * N_ + pt * 64 + c0 * 16;
#pragma unroll
            for (int v = 0; v < 4; ++v)
                *(float4*)&Bt[k * 68 + c0 * 16 + v * 4] = *(const float4*)&src[v * 4];
        }
        __syncthreads();

        float acc[4][4] = {};
#pragma unroll 8
        for (int kk = 0; kk < 64; ++kk) {
            const float4 a  = *(const float4*)&At[kk * 68 + ty * 4];
            const float4 bb = *(const float4*)&Bt[kk * 68 + tx * 4];
            acc[0][0] += a.x*bb.x; acc[0][1] += a.x*bb.y; acc[0][2] += a.x*bb.z; acc[0][3] += a.x*bb.w;
            acc[1][0] += a.y*bb.x; acc[1][1] += a.y*bb.y; acc[1][2] += a.y*bb.z; acc[1][3] += a.y*bb.w;
            acc[2][0] += a.z*bb.x; acc[2][1] += a.z*bb.y; acc[2][2] += a.z*bb.z; acc[2][3] += a.z*bb.w;
            acc[3][0] += a.w*bb.x; acc[3][1] += a.w*bb.y; acc[3][2] += a.w*bb.z; acc[3][3] += a.w*bb.w;
        }

        float* sout = Spart + ((size_t)(kq * 4 + b) * N_ + it * 64 + ty * 4) * N_ + pt * 64 + tx * 4;
#pragma unroll
        for (int ri = 0; ri < 4; ++ri)
            *(float4*)&sout[(size_t)ri * N_] =
                make_float4(acc[ri][0], acc[ri][1], acc[ri][2], acc[ri][3]);
    }

    grid.sync();

    // ================= Phase 3: tgemm (120 jobs): Tpart[kp][b] tiles
    if (blk < 120) {
        const int b = blk / 30;
        const int r2 = blk % 30;
        int it, nt, kp;
        if (r2 < 1)       { it = 0; nt = 0;              kp = 0; }
        else if (r2 < 5)  { it = 1; const int q = r2-1;  nt = q >> 1; kp = q & 1; }
        else if (r2 < 14) { it = 2; const int q = r2-5;  nt = q / 3;  kp = q % 3; }
        else              { it = 3; const int q = r2-14; nt = q >> 2; kp = q & 3; }

        // ---- stage A: S rows it*64.., cols kp*64.., sum it+1 slabs, diag mask
        {
            const int i_loc = tid >> 2, c0 = tid & 3;
            float av[16];
#pragma unroll
            for (int e = 0; e < 16; ++e) av[e] = 0.f;
            for (int q = 0; q <= it; ++q) {
                const float* src = Spart + ((size_t)(q * 4 + b) * N_ + it * 64 + i_loc) * N_
                                 + kp * 64 + c0 * 16;
#pragma unroll
                for (int v = 0; v < 4; ++v) {
                    const float4 f = *(const float4*)&src[v * 4];
                    av[v*4+0] += f.x; av[v*4+1] += f.y; av[v*4+2] += f.z; av[v*4+3] += f.w;
                }
            }
            if (kp == it) {
#pragma unroll
                for (int e = 0; e < 16; ++e)
                    if (c0 * 16 + e > i_loc) av[e] = 0.f;
            }
#pragma unroll
            for (int e = 0; e < 16; ++e) At[(c0 * 16 + e) * 68 + i_loc] = av[e];
        }
        // ---- stage B: QwT rows kp*64.., cols nt*64..
        {
            const int k = tid >> 2, c0 = tid & 3;
            const float* src = QwT + (size_t)(kp * 64 + k) * N_ + nt * 64 + c0 * 16;
#pragma unroll
            for (int v = 0; v < 4; ++v)
                *(float4*)&Bt[k * 68 + c0 * 16 + v * 4] = *(const float4*)&src[v * 4];
        }
        __syncthreads();

        float acc[4][4] = {};
#pragma unroll 8
        for (int kk = 0; kk < 64; ++kk) {
            const float4 a  = *(const float4*)&At[kk * 68 + ty * 4];
            const float4 bb = *(const float4*)&Bt[kk * 68 + tx * 4];
            acc[0][0] += a.x*bb.x; acc[0][1] += a.x*bb.y; acc[0][2] += a.x*bb.z; acc[0][3] += a.x*bb.w;
            acc[1][0] += a.y*bb.x; acc[1][1] += a.y*bb.y; acc[1][2] += a.y*bb.z; acc[1][3] += a.y*bb.w;
            acc[2][0] += a.z*bb.x; acc[2][1] += a.z*bb.y; acc[2][2] += a.z*bb.z; acc[2][3] += a.z*bb.w;
            acc[3][0] += a.w*bb.x; acc[3][1] += a.w*bb.y; acc[3][2] += a.w*bb.z; acc[3][3] += a.w*bb.w;
        }

        float* tout = Tpart + ((size_t)(kp * 4 + b) * N_ + it * 64 + ty * 4) * N_ + nt * 64 + tx * 4;
#pragma unroll
        for (int ri = 0; ri < 4; ++ri)
            *(float4*)&tout[(size_t)ri * N_] =
                make_float4(acc[ri][0], acc[ri][1], acc[ri][2], acc[ri][3]);
    }

    grid.sync();

    // ================= Phase 4: final (256 jobs): fit + avg + out
    if (blk < 256) {
        const int mt = blk & 7, rt = (blk >> 3) & 7, b = blk >> 6;
        const int it_eff = rt >> 1;
        const int ibase  = (rt & 1) * 32;
        const float* __restrict__ Xb = X + (size_t)b * N_ * E_;

        float* const Atf = lds;                    // [64][36]
        float* const Btf = lds + 64 * 36;          // [64][68]
        float* const avr = lds + 64 * 36 + 64 * 68;// [32][9]

        float acc[2][4] = {};
        float avgacc = 0.f;

        for (int kn = 0; kn <= it_eff; ++kn) {
            {
                const int r = tid >> 3, c0 = tid & 7;
                float tvv[8], gvv[8];
#pragma unroll
                for (int e = 0; e < 8; ++e) { tvv[e] = 0.f; gvv[e] = 0.f; }
                for (int q = 0; q <= it_eff; ++q) {
                    const float* src = Tpart + ((size_t)(q * 4 + b) * N_ + rt * 32 + r) * N_
                                     + kn * 64 + c0 * 8;
#pragma unroll
                    for (int v = 0; v < 2; ++v) {
                        const float4 f = *(const float4*)&src[v * 4];
                        tvv[v*4+0] += f.x; tvv[v*4+1] += f.y; tvv[v*4+2] += f.z; tvv[v*4+3] += f.w;
                    }
                }
#pragma unroll
                for (int q = 0; q < 4; ++q) {
                    const float* src = Gpart + ((size_t)(q * 4 + b) * N_ + rt * 32 + r) * N_
                                     + kn * 64 + c0 * 8;
#pragma unroll
                    for (int v = 0; v < 2; ++v) {
                        const float4 f = *(const float4*)&src[v * 4];
                        gvv[v*4+0] += f.x; gvv[v*4+1] += f.y; gvv[v*4+2] += f.z; gvv[v*4+3] += f.w;
                    }
                }
                if (kn == it_eff) {
#pragma unroll
                    for (int e = 0; e < 8; ++e)
                        if (c0 * 8 + e > ibase + r) tvv[e] = 0.f;
                }
#pragma unroll
                for (int e = 0; e < 8; ++e) {
                    avgacc += tvv[e] * gvv[e];
                    Atf[(c0 * 8 + e) * 36 + r] = tvv[e];
                }
            }
            {
                const int k = tid >> 2, c0 = tid & 3;
                const float* src = Xb + (size_t)(kn * 64 + k) * E_ + mt * 64 + c0 * 16;
#pragma unroll
                for (int v = 0; v < 4; ++v)
                    *(float4*)&Btf[k * 68 + c0 * 16 + v * 4] = *(const float4*)&src[v * 4];
            }
            __syncthreads();

#pragma unroll 8
            for (int kk = 0; kk < 64; ++kk) {
                const float2 a  = *(const float2*)&Atf[kk * 36 + ty * 2];
                const float4 bb = *(const float4*)&Btf[kk * 68 + tx * 4];
                acc[0][0] += a.x*bb.x; acc[0][1] += a.x*bb.y; acc[0][2] += a.x*bb.z; acc[0][3] += a.x*bb.w;
                acc[1][0] += a.y*bb.x; acc[1][1] += a.y*bb.y; acc[1][2] += a.y*bb.z; acc[1][3] += a.y*bb.w;
            }
            __syncthreads();
        }

        avr[(tid >> 3) * 9 + (tid & 7)] = avgacc;
        __syncthreads();

#pragma unroll
        for (int ri = 0; ri < 2; ++ri) {
            const int row = ty * 2 + ri;
            float avg = 0.f;
#pragma unroll
            for (int c = 0; c < 8; ++c) avg += avr[row * 9 + c];
            const int gi = rt * 32 + row;
            const float4 xv = *(const float4*)&Xb[(size_t)gi * E_ + mt * 64 + tx * 4];
            float4 ov;
            ov.x = xv.x * (1.f + acc[ri][0] - avg);
            ov.y = xv.y * (1.f + acc[ri][1] - avg);
            ov.z = xv.z * (1.f + acc[ri][2] - avg);
            ov.w = xv.w * (1.f + acc[ri][3] - avg);
            *(float4*)&out[((size_t)b * N_ + gi) * E_ + mt * 64 + tx * 4] = ov;
        }
    }
}

// ---------------------------------------------------------------------------
extern "C" void kernel_launch(void* const* d_in, const int* in_sizes, int n_in,
                              void* d_out, int out_size, void* d_ws, size_t ws_size,
                              hipStream_t stream) {
    const float* X  = (const float*)d_in[0];   // (B,N,E)
    const float* Qw = (const float*)d_in[1];   // (N,N)
    const float* Kw = (const float*)d_in[2];   // (N,N)
    float* out = (float*)d_out;                // (B,N,E)
    float* ws  = (float*)d_ws;

    void* args[] = { (void*)&X, (void*)&Qw, (void*)&Kw, (void*)&ws, (void*)&out };
    hipLaunchCooperativeKernel((const void*)mono_kernel, dim3(272), dim3(16, 16),
                               args, 0, stream);
}

// Round 11
// 82.595 us; speedup vs baseline: 2.5002x; 2.5002x over previous
//
#include <hip/hip_runtime.h>

// Problem constants: B=4, N=256, E=512, fp32.
#define B_ 4
#define N_ 256
#define E_ 512

// ws layout (floats): QwT[256*256], Gpart[16][256*256]  (~4.25 MB total)

// ---------------------------------------------------------------------------
// prep_kernel: grid (4,4,17), block (16,16).  [unchanged, proven]
//  bz 0..15: split-K Gram partial; bz==16: Qw transpose.
// ---------------------------------------------------------------------------
__global__ __launch_bounds__(256) void prep_kernel(
    const float* __restrict__ X, const float* __restrict__ Qw,
    float* __restrict__ QwT, float* __restrict__ Gpart) {

    const int bx = blockIdx.x, by = blockIdx.y, bz = blockIdx.z;
    const int tx = threadIdx.x, ty = threadIdx.y;
    const int tid = ty * 16 + tx;

    if (bz == 16) {
        __shared__ float tt[64][68];
        const int r = tid >> 2, c0 = tid & 3;
#pragma unroll
        for (int cc = 0; cc < 4; ++cc) {
            const int c = (c0 + cc * 4) * 4;
            const float4 v = *(const float4*)&Qw[(by * 64 + r) * N_ + bx * 64 + c];
            tt[c + 0][r] = v.x; tt[c + 1][r] = v.y;
            tt[c + 2][r] = v.z; tt[c + 3][r] = v.w;
        }
        __syncthreads();
#pragma unroll
        for (int cc = 0; cc < 4; ++cc) {
            const int c = (c0 + cc * 4) * 4;
            const float4 v = *(const float4*)&tt[r][c];
            *(float4*)&QwT[(bx * 64 + r) * N_ + by * 64 + c] = v;
        }
        return;
    }

    const int b = bz >> 2, kq = bz & 3;
    const float* __restrict__ Xb = X + (size_t)b * N_ * E_;
    __shared__ float At[32][68];
    __shared__ float Bt[32][68];
    float acc[4][4] = {};
    const int r = tid >> 2, c0 = tid & 3;

    for (int k0 = kq * 128; k0 < kq * 128 + 128; k0 += 32) {
        {
            const float4 va = *(const float4*)&Xb[(size_t)(by * 64 + r) * E_ + k0 + c0 * 8];
            const float4 vb = *(const float4*)&Xb[(size_t)(by * 64 + r) * E_ + k0 + c0 * 8 + 4];
            At[c0*8+0][r] = va.x; At[c0*8+1][r] = va.y; At[c0*8+2][r] = va.z; At[c0*8+3][r] = va.w;
            At[c0*8+4][r] = vb.x; At[c0*8+5][r] = vb.y; At[c0*8+6][r] = vb.z; At[c0*8+7][r] = vb.w;
            const float4 wa = *(const float4*)&Xb[(size_t)(bx * 64 + r) * E_ + k0 + c0 * 8];
            const float4 wb = *(const float4*)&Xb[(size_t)(bx * 64 + r) * E_ + k0 + c0 * 8 + 4];
            Bt[c0*8+0][r] = wa.x; Bt[c0*8+1][r] = wa.y; Bt[c0*8+2][r] = wa.z; Bt[c0*8+3][r] = wa.w;
            Bt[c0*8+4][r] = wb.x; Bt[c0*8+5][r] = wb.y; Bt[c0*8+6][r] = wb.z; Bt[c0*8+7][r] = wb.w;
        }
        __syncthreads();
#pragma unroll
        for (int kk = 0; kk < 32; ++kk) {
            const float4 a  = *(const float4*)&At[kk][ty * 4];
            const float4 bb = *(const float4*)&Bt[kk][tx * 4];
            acc[0][0] += a.x*bb.x; acc[0][1] += a.x*bb.y; acc[0][2] += a.x*bb.z; acc[0][3] += a.x*bb.w;
            acc[1][0] += a.y*bb.x; acc[1][1] += a.y*bb.y; acc[1][2] += a.y*bb.z; acc[1][3] += a.y*bb.w;
            acc[2][0] += a.z*bb.x; acc[2][1] += a.z*bb.y; acc[2][2] += a.z*bb.z; acc[2][3] += a.z*bb.w;
            acc[3][0] += a.w*bb.x; acc[3][1] += a.w*bb.y; acc[3][2] += a.w*bb.z; acc[3][3] += a.w*bb.w;
        }
        __syncthreads();
    }
    float* gout = Gpart + ((size_t)(kq * 4 + b) * N_ + by * 64 + ty * 4) * N_ + bx * 64 + tx * 4;
#pragma unroll
    for (int qi = 0; qi < 4; ++qi)
        *(float4*)&gout[(size_t)qi * N_] =
            make_float4(acc[qi][0], acc[qi][1], acc[qi][2], acc[qi][3]);
}

__device__ __forceinline__ void fma4(float4& a, float c, const float4& v) {
    a.x += c * v.x; a.y += c * v.y; a.z += c * v.z; a.w += c * v.w;
}

// ---------------------------------------------------------------------------
// fused: RPB=2, 512 threads (8 waves).  grid 512 -> 2 blocks/CU, 16 waves/CU
// = 4 waves/SIMD (2x R6's TLP at identical traffic).  Complementary pairing:
// blocks c and c+256 (same CU) get spans 2j and 254-2j.
// Waves split the n/p range 8-way; 16KB LDS reduce buffer; phase D in two
// row-rounds.  Masks/zero-padding identical to the proven R6 math.
// ---------------------------------------------------------------------------
__global__ __launch_bounds__(512) void fused_kernel(
    const float* __restrict__ X, const float* __restrict__ Kw,
    const float* __restrict__ QwT, const float* __restrict__ Gpart,
    float* __restrict__ out) {

    const int blk = blockIdx.x;          // 0..511
    const int b   = blk >> 7;
    const int j   = blk & 127;
    const int jr  = (b >= 2) ? (127 - j) : j;
    const int i0  = jr * 2;
    const int imax = i0 + 1;

    const int tid  = threadIdx.x;        // 0..511
    const int lane = tid & 63, wid = tid >> 6;

    const float4* __restrict__ Xb4 = (const float4*)(X + (size_t)b * N_ * E_);
    const float4* __restrict__ Kw4 = (const float4*)Kw;     // row stride 64
    const float4* __restrict__ Qt4 = (const float4*)QwT;    // row stride 64

    __shared__ float  xi[2][E_];        // 4 KB
    __shared__ float  gT[N_][2];        // 2 KB (zero-padded beyond row's i)
    __shared__ float  sT[N_][2];
    __shared__ float  tT[N_][2];
    __shared__ float4 sp[8][2][64];     // 16 KB reduce buffer (B/C/D union)
    __shared__ float  avgv[2];
    __shared__ float  red[8];
    float* const spf  = (float*)sp;
    float4* const spD = &sp[0][0][0];   // D view: [8][128] float4

    const int p  = tid & 255;           // coefficient index
    const int r  = tid >> 8;            // row 0/1
    const int ir = r ? imax : i0;

    // ---- prologue: xi rows; gT from Gpart (sum 4 K-quarters), masked
    if (tid < 256) {
        const int rr = tid >> 7, c = tid & 127;
        ((float4*)xi[rr])[c] = Xb4[(size_t)(i0 + rr) * 128 + c];
    }
    {
        float s = 0.f;
#pragma unroll
        for (int q = 0; q < 4; ++q)
            s += Gpart[((size_t)(q * 4 + b) * N_ + (i0 + r)) * N_ + p];
        gT[p][r] = (p <= ir) ? s : 0.f;
    }
    __syncthreads();

    // loop bound: multiple of 32; per-wave chunk multiple of 4
    const int Mc  = (imax + 32) & ~31;
    const int cnt = Mc >> 3;
    const int nb  = wid * cnt;

    // ---- Phase B: s[p'][r'] = sum_n gT[n][r'] * Kw[n][p']   (waves split n)
    {
        float4 a0 = {0,0,0,0}, a1 = {0,0,0,0};
        for (int t4 = 0; t4 < cnt; t4 += 4) {
#pragma unroll
            for (int u = 0; u < 4; ++u) {
                const int n = nb + t4 + u;
                const float4 kv = Kw4[(size_t)n * 64 + lane];
                const float2 g2 = *(const float2*)&gT[n][0];
                fma4(a0, g2.x, kv);
                fma4(a1, g2.y, kv);
            }
        }
        sp[wid][0][lane] = a0;
        sp[wid][1][lane] = a1;
    }
    __syncthreads();
    {
        float v = 0.f;
#pragma unroll
        for (int w = 0; w < 8; ++w) v += spf[(w * 2 + r) * 256 + p];
        sT[p][r] = (p <= ir) ? v : 0.f;
    }
    __syncthreads();

    // ---- Phase C: t[n'][r'] = sum_p sT[p][r'] * QwT[p][n']   (waves split p)
    {
        float4 a0 = {0,0,0,0}, a1 = {0,0,0,0};
        for (int t4 = 0; t4 < cnt; t4 += 4) {
#pragma unroll
            for (int u = 0; u < 4; ++u) {
                const int pp = nb + t4 + u;
                const float4 qv = Qt4[(size_t)pp * 64 + lane];
                const float2 s2 = *(const float2*)&sT[pp][0];
                fma4(a0, s2.x, qv);
                fma4(a1, s2.y, qv);
            }
        }
        sp[wid][0][lane] = a0;
        sp[wid][1][lane] = a1;
    }
    __syncthreads();
    {
        float v = 0.f;
#pragma unroll
        for (int w = 0; w < 8; ++w) v += spf[(w * 2 + r) * 256 + p];
        tT[p][r] = (p <= ir) ? v : 0.f;
    }
    __syncthreads();

    // ---- avg[r] = sum_n tT[n][r] * gT[n][r]  (waves 0-3: r=0, 4-7: r=1)
    {
        float v = tT[p][r] * gT[p][r];
#pragma unroll
        for (int off = 32; off > 0; off >>= 1)
            v += __shfl_xor(v, off, 64);
        if (lane == 0) red[wid] = v;
    }
    __syncthreads();
    if (tid == 0) {
        avgv[0] = red[0] + red[1] + red[2] + red[3];
        avgv[1] = red[4] + red[5] + red[6] + red[7];
    }
    __syncthreads();

    // ---- Phase D: fit[r'][m] = sum_n tT[n][r'] * X[n][m]   (waves split n)
    float4 f00 = {0,0,0,0}, f01 = {0,0,0,0};
    float4 f10 = {0,0,0,0}, f11 = {0,0,0,0};
    for (int t2 = 0; t2 < cnt; t2 += 2) {
#pragma unroll
        for (int u = 0; u < 2; ++u) {
            const int n = nb + t2 + u;
            const float4 xa = Xb4[(size_t)n * 128 + lane];
            const float4 xb = Xb4[(size_t)n * 128 + 64 + lane];
            const float2 t2v = *(const float2*)&tT[n][0];
            fma4(f00, t2v.x, xa); fma4(f01, t2v.x, xb);
            fma4(f10, t2v.y, xa); fma4(f11, t2v.y, xb);
        }
    }
    // row 0 reduce + store  (sp free: last consumed before the avg sync)
    spD[wid * 128 + lane]      = f00;
    spD[wid * 128 + 64 + lane] = f01;
    __syncthreads();
    {
        float fit = 0.f;
#pragma unroll
        for (int w = 0; w < 8; ++w) fit += spf[w * 512 + tid];
        out[((size_t)b * N_ + i0) * E_ + tid] = xi[0][tid] * (1.f + fit - avgv[0]);
    }
    __syncthreads();
    // row 1 reduce + store
    spD[wid * 128 + lane]      = f10;
    spD[wid * 128 + 64 + lane] = f11;
    __syncthreads();
    {
        float fit = 0.f;
#pragma unroll
        for (int w = 0; w < 8; ++w) fit += spf[w * 512 + tid];
        out[((size_t)b * N_ + imax) * E_ + tid] = xi[1][tid] * (1.f + fit - avgv[1]);
    }
}

// ---------------------------------------------------------------------------
extern "C" void kernel_launch(void* const* d_in, const int* in_sizes, int n_in,
                              void* d_out, int out_size, void* d_ws, size_t ws_size,
                              hipStream_t stream) {
    const float* X  = (const float*)d_in[0];   // (B,N,E)
    const float* Qw = (const float*)d_in[1];   // (N,N)
    const float* Kw = (const float*)d_in[2];   // (N,N)
    float* out = (float*)d_out;                // (B,N,E)

    float* QwT   = (float*)d_ws;               // 256 KB
    float* Gpart = QwT + (size_t)N_ * N_;      // 16 * 256 KB = 4 MB

    prep_kernel<<<dim3(4, 4, 17), dim3(16, 16), 0, stream>>>(X, Qw, QwT, Gpart);
    fused_kernel<<<B_ * (N_ / 2), 512, 0, stream>>>(X, Kw, QwT, Gpart, out);
}